// Round 1
// baseline (460.154 us; speedup 1.0000x reference)
//
#include <hip/hip_runtime.h>

#define NW 12
#define NL 3
#define DIM 4096
#define NPAIR 2048
#define BLK 256
#define BATCH 8192

// One block per batch sample. Statevector (4096 complex) lives in LDS.
// Gates fused: G = RY(b) * RX(a)  (2x2 complex).
// CNOT ring folded into a single bit-permutation per layer.
// Head (q @ head_w.T + head_b) folded into the probability reduction.
__global__ __launch_bounds__(BLK) void qsim_kernel(
    const float* __restrict__ sr, const float* __restrict__ si,
    const float* __restrict__ wts, const float* __restrict__ hw,
    const float* __restrict__ hb, float* __restrict__ out) {
  __shared__ float s_re[DIM], s_im[DIM];
  __shared__ float g_re[NL * NW][4], g_im[NL * NW][4];
  __shared__ float enc_re[NW][2], enc_im[NW][2];
  __shared__ float T_re[3][16], T_im[3][16];
  __shared__ float Wt[3][16];
  __shared__ float wave_part[BLK / 64];

  const int t = threadIdx.x;
  const int s = blockIdx.x;

  // ---- Phase A (disjoint thread ranges, no dependencies) ----
  // Fused layer gates G = RY(b)*RX(a):
  //   G00 = cb*ca + i*sb*sa    G01 = -sb*ca - i*cb*sa
  //   G10 = sb*ca - i*cb*sa    G11 =  cb*ca - i*sb*sa
  if (t < NL * NW) {
    float a = wts[t * 2 + 0] * 0.5f;
    float b = wts[t * 2 + 1] * 0.5f;
    float sa, ca, sb, cb;
    sincosf(a, &sa, &ca);
    sincosf(b, &sb, &cb);
    g_re[t][0] = cb * ca;  g_im[t][0] =  sb * sa;
    g_re[t][1] = -sb * ca; g_im[t][1] = -cb * sa;
    g_re[t][2] = sb * ca;  g_im[t][2] = -cb * sa;
    g_re[t][3] = cb * ca;  g_im[t][3] = -sb * sa;
  }
  // Per-sample single-qubit encoded states: RY(a)RX(a)|0> = (c^2 + i s^2, sc - i sc)
  if (t >= 64 && t < 64 + NW) {
    int w = t - 64;
    float ang = atan2f(si[(size_t)s * DIM + w], sr[(size_t)s * DIM + w]) * 0.5f;
    float sn, cs;
    sincosf(ang, &sn, &cs);
    enc_re[w][0] = cs * cs;  enc_im[w][0] = sn * sn;
    enc_re[w][1] = sn * cs;  enc_im[w][1] = -sn * cs;
  }
  // Additive head-weight tables: w(x) = Wt0[x>>8] + Wt1[(x>>4)&15] + Wt2[x&15]
  if (t >= 128 && t < 128 + 48) {
    int idx = t - 128;
    int g = idx >> 4, m = idx & 15;
    float acc = 0.f;
    for (int k = 0; k < 4; ++k) {
      float sgn = ((m >> (3 - k)) & 1) ? -1.f : 1.f;
      acc += hw[4 * g + k] * sgn;
    }
    Wt[g][m] = acc;
  }
  __syncthreads();

  // ---- Phase B: group product tables for the product-state encoding ----
  if (t < 48) {
    int g = t >> 4, m = t & 15;
    float pr = 1.f, pi = 0.f;
    for (int k = 0; k < 4; ++k) {
      int bit = (m >> (3 - k)) & 1;
      float fr = enc_re[4 * g + k][bit], fi = enc_im[4 * g + k][bit];
      float nr = pr * fr - pi * fi;
      float ni = pr * fi + pi * fr;
      pr = nr; pi = ni;
    }
    T_re[g][m] = pr; T_im[g][m] = pi;
  }
  __syncthreads();

  // ---- Phase C: materialize initial (product) state into LDS ----
  {
    float t2r = T_re[2][t & 15], t2i = T_im[2][t & 15];  // x&15 == t&15
    for (int j = 0; j < 16; ++j) {
      int x = j * BLK + t;
      int g0 = x >> 8, g1 = (x >> 4) & 15;
      float ar = T_re[0][g0], ai = T_im[0][g0];
      float br = T_re[1][g1], bi = T_im[1][g1];
      float pr = ar * br - ai * bi;
      float pi = ar * bi + ai * br;
      s_re[x] = pr * t2r - pi * t2i;
      s_im[x] = pr * t2i + pi * t2r;
    }
  }

  // ---- Phase D: 3 layers of (12 fused rotations + CNOT-ring permutation) ----
  for (int l = 0; l < NL; ++l) {
    for (int i = 0; i < NW; ++i) {
      __syncthreads();
      int gi = l * NW + i;
      float g00r = g_re[gi][0], g00i = g_im[gi][0];
      float g01r = g_re[gi][1], g01i = g_im[gi][1];
      float g10r = g_re[gi][2], g10i = g_im[gi][2];
      float g11r = g_re[gi][3], g11i = g_im[gi][3];
      int p = 11 - i;                 // wire i acts on bit (11-i); wire 0 = MSB
      int mask = (1 << p) - 1;
      for (int k = t; k < NPAIR; k += BLK) {
        int x0 = ((k & ~mask) << 1) | (k & mask);
        int x1 = x0 | (1 << p);
        float ar = s_re[x0], ai = s_im[x0];
        float br = s_re[x1], bi = s_im[x1];
        float n0r = g00r * ar - g00i * ai + g01r * br - g01i * bi;
        float n0i = g00r * ai + g00i * ar + g01r * bi + g01i * br;
        float n1r = g10r * ar - g10i * ai + g11r * br - g11i * bi;
        float n1i = g10r * ai + g10i * ar + g11r * bi + g11i * br;
        s_re[x0] = n0r; s_im[x0] = n0i;
        s_re[x1] = n1r; s_im[x1] = n1i;
      }
    }
    // CNOT ring = prefix-XOR bit permutation:
    //  new wire-bit i (i>=1) = XOR of wire-bits 0..i  -> suffix-xor over bit
    //  positions; new wire-bit 0 = parity(x) ^ old wire-bit 0.
    __syncthreads();
    float rr[16], ri[16];
    int xp[16];
    for (int j = 0; j < 16; ++j) {
      int x = j * BLK + t;
      rr[j] = s_re[x]; ri[j] = s_im[x];
      int y = x ^ (x >> 1);
      y ^= y >> 2;
      y ^= y >> 4;
      y ^= y >> 8;
      int b0 = (__popc(x) ^ (x >> 11)) & 1;
      xp[j] = (y & 0x7FF) | (b0 << 11);
    }
    __syncthreads();
    for (int j = 0; j < 16; ++j) {
      s_re[xp[j]] = rr[j];
      s_im[xp[j]] = ri[j];
    }
  }

  // ---- Phase E: y = sum_x |psi_x|^2 * w(x) + b ----
  __syncthreads();
  float part = 0.f;
  float w2 = Wt[2][t & 15];
  for (int j = 0; j < 16; ++j) {
    int x = j * BLK + t;
    float re = s_re[x], im = s_im[x];
    float w = Wt[0][x >> 8] + Wt[1][(x >> 4) & 15] + w2;
    part += (re * re + im * im) * w;
  }
  for (int off = 32; off > 0; off >>= 1)
    part += __shfl_down(part, off, 64);
  if ((t & 63) == 0) wave_part[t >> 6] = part;
  __syncthreads();
  if (t == 0)
    out[s] = wave_part[0] + wave_part[1] + wave_part[2] + wave_part[3] + hb[0];
}

extern "C" void kernel_launch(void* const* d_in, const int* in_sizes, int n_in,
                              void* d_out, int out_size, void* d_ws, size_t ws_size,
                              hipStream_t stream) {
  const float* sr  = (const float*)d_in[0];
  const float* si  = (const float*)d_in[1];
  const float* wts = (const float*)d_in[2];
  const float* hw  = (const float*)d_in[3];
  const float* hb  = (const float*)d_in[4];
  float* out = (float*)d_out;
  qsim_kernel<<<BATCH, BLK, 0, stream>>>(sr, si, wts, hw, hb, out);
}

// Round 2
// 244.503 us; speedup vs baseline: 1.8820x; 1.8820x over previous
//
#include <hip/hip_runtime.h>

#define BLK 256
#define BATCH 8192

// ---------------- GF(2) 12x12 matrix machinery (all compile-time) ----------
struct M12 { unsigned r[12]; };

constexpr M12 mp_matrix() {
  // CNOT-ring permutation y = P x (from the verified round-1 kernel):
  // y_p = x_p ^ ... ^ x_11 for p=0..10 ; y_11 = x_0 ^ ... ^ x_10
  M12 m{};
  for (int p = 0; p <= 10; ++p) m.r[p] = (0xFFFu >> p) << p;
  m.r[11] = 0x7FFu;
  return m;
}
constexpr M12 mmul(const M12 a, const M12 b) {  // c(x) = a(b(x))
  M12 c{};
  for (int p = 0; p < 12; ++p) {
    unsigned acc = 0;
    for (int q = 0; q < 12; ++q)
      if ((a.r[p] >> q) & 1u) acc ^= b.r[q];
    c.r[p] = acc;
  }
  return c;
}
constexpr M12 minv(const M12 a0) {  // Gauss-Jordan over GF(2)
  unsigned a[12], v[12];
  for (int i = 0; i < 12; ++i) { a[i] = a0.r[i]; v[i] = 1u << i; }
  for (int c = 0; c < 12; ++c) {
    int piv = c;
    while (!((a[piv] >> c) & 1u)) ++piv;
    unsigned ta = a[piv], tv = v[piv];
    a[piv] = a[c]; v[piv] = v[c]; a[c] = ta; v[c] = tv;
    for (int r2 = 0; r2 < 12; ++r2)
      if (r2 != c && ((a[r2] >> c) & 1u)) { a[r2] ^= a[c]; v[r2] ^= v[c]; }
  }
  M12 out{};
  for (int i = 0; i < 12; ++i) out.r[i] = v[i];
  return out;
}
constexpr unsigned mcol(const M12 m, int p) {
  unsigned c = 0;
  for (int q = 0; q < 12; ++q) c |= ((m.r[q] >> p) & 1u) << q;
  return c;
}

constexpr M12 MP  = mp_matrix();
constexpr M12 MI  = minv(MP);
constexpr M12 MI2 = mmul(MI, MI);
constexpr M12 MP2 = mmul(MP, MP);
constexpr M12 MP3 = mmul(MP2, MP);

constexpr bool check_inv() {
  M12 id = mmul(MP, MI);
  for (int i = 0; i < 12; ++i)
    if (id.r[i] != (1u << i)) return false;
  return true;
}
static_assert(check_inv(), "MI is not the inverse of MP");
constexpr bool check_rm() {
  for (int p = 0; p < 12; ++p) {
    if (!(__builtin_popcount(mcol(MI, p)  & MP.r[p])  & 1)) return false;
    if (!(__builtin_popcount(mcol(MI2, p) & MP2.r[p]) & 1)) return false;
  }
  return true;
}
static_assert(check_rm(), "role-row / mask inner product must be 1");

// ---------------- gate application on register-resident state ---------------
// State: lane holds amplitudes B[z], z = (lane<<6) | j, j = 0..63.
// Gate for layer LIDX (0 -> ref layer 1, 1 -> ref layer 2) on bit P:
//   pair mask m = col_P(MP^-(LIDX+1)), role row rw = row_P(MP^(LIDX+1)).
template<int LIDX, int P>
__device__ __forceinline__ void apply_gate(float (&vr)[64], float (&vi)[64],
                                           const int lane,
                                           const float* __restrict__ gt) {
  constexpr unsigned m  = (LIDX == 0) ? mcol(MI, P) : mcol(MI2, P);
  constexpr unsigned rw = (LIDX == 0) ? MP.r[P]     : MP2.r[P];
  static_assert((__builtin_popcount(m & rw) & 1) == 1, "bad role split");
  constexpr int mlane = (int)(m >> 6), mreg = (int)(m & 63u);
  constexpr int rlane = (int)(rw >> 6), rreg = (int)(rw & 63u);

  const float* g = gt + (LIDX * 12 + (11 - P)) * 8;
  const float g00r = g[0], g00i = g[1], g01r = g[2], g01i = g[3];
  const float g10r = g[4], g10i = g[5], g11r = g[6], g11i = g[7];
  // Per-lane role flip folded into the gate matrix (anti-transpose).
  const bool hl = (__builtin_popcount(lane & rlane) & 1) != 0;
  const float a00r = hl ? g11r : g00r, a00i = hl ? g11i : g00i;
  const float a01r = hl ? g10r : g01r, a01i = hl ? g10i : g01i;
  const float a10r = hl ? g01r : g10r, a10i = hl ? g01i : g10i;
  const float a11r = hl ? g00r : g11r, a11i = hl ? g00i : g11i;

  if constexpr (mlane == 0) {
    // pure in-register pairs (j, j^mreg); element with parity(j&rreg)==0 is role-0
    #pragma unroll
    for (int j = 0; j < 64; ++j) {
      if ((__builtin_popcount(j & rreg) & 1) == 0) {
        const int k = j ^ mreg;
        const float ar = vr[j], ai = vi[j], br = vr[k], bi = vi[k];
        vr[j] = a00r * ar - a00i * ai + a01r * br - a01i * bi;
        vi[j] = a00r * ai + a00i * ar + a01r * bi + a01i * br;
        vr[k] = a10r * ar - a10i * ai + a11r * br - a11i * bi;
        vi[k] = a10r * ai + a10i * ar + a11r * bi + a11i * br;
      }
    }
  } else {
    // cross-lane: partner value at (lane^mlane, j^mreg) via shfl_xor.
    // Groups must be closed under ^mreg (fetch-all-then-update within group),
    // since partner lanes update in lockstep.
    constexpr int GRP   = (mreg < 16) ? 16 : 32;
    constexpr int HIGH  = mreg & 48;
    constexpr int CSTEP = (HIGH >= 32) ? 16 : GRP;
    #pragma unroll
    for (int grp = 0; grp < 64 / GRP; ++grp) {
      const int c = grp * CSTEP;
      float pr[GRP], pi[GRP];
      #pragma unroll
      for (int u = 0; u < GRP; ++u) {
        const int j = (HIGH >= 32) ? ((u < 16) ? (c + u) : ((c + u - 16) ^ HIGH))
                                   : (c + u);
        const int k = j ^ mreg;
        pr[u] = __shfl_xor(vr[k], mlane, 64);
        pi[u] = __shfl_xor(vi[k], mlane, 64);
      }
      #pragma unroll
      for (int u = 0; u < GRP; ++u) {
        const int j = (HIGH >= 32) ? ((u < 16) ? (c + u) : ((c + u - 16) ^ HIGH))
                                   : (c + u);
        const float ar = vr[j], ai = vi[j];
        const float br = pr[u], bi = pi[u];
        if ((__builtin_popcount(j & rreg) & 1) == 0) {
          vr[j] = a00r * ar - a00i * ai + a01r * br - a01i * bi;
          vi[j] = a00r * ai + a00i * ar + a01r * bi + a01i * br;
        } else {
          vr[j] = a10r * br - a10i * bi + a11r * ar - a11i * ai;
          vi[j] = a10r * bi + a10i * br + a11r * ai + a11i * ar;
        }
      }
    }
  }
}

// ---------------------------------- kernel ----------------------------------
__global__ __launch_bounds__(BLK, 2) void qsim_kernel(
    const float* __restrict__ sr, const float* __restrict__ si,
    const float* __restrict__ wts, const float* __restrict__ hw,
    const float* __restrict__ hb, float* __restrict__ out) {
  __shared__ float gt[24 * 8];     // fused RY*RX gates, layers 1..2
  __shared__ float4 qv[4][12];     // per-wave per-wire 2-vector after enc+layer0

  const int t = threadIdx.x;
  const int lane = t & 63;
  const int w = t >> 6;
  const int s = blockIdx.x * 4 + w;

  // Phase A: block-shared fused gate table for ref layers 1,2
  if (t < 24) {
    const int l = 1 + t / 12, i = t % 12;
    const float a = wts[(l * 12 + i) * 2 + 0] * 0.5f;
    const float b = wts[(l * 12 + i) * 2 + 1] * 0.5f;
    float sa, ca, sb, cb;
    sincosf(a, &sa, &ca);
    sincosf(b, &sb, &cb);
    gt[t * 8 + 0] = cb * ca;  gt[t * 8 + 1] =  sb * sa;   // g00
    gt[t * 8 + 2] = -sb * ca; gt[t * 8 + 3] = -cb * sa;   // g01
    gt[t * 8 + 4] = sb * ca;  gt[t * 8 + 5] = -cb * sa;   // g10
    gt[t * 8 + 6] = cb * ca;  gt[t * 8 + 7] = -sb * sa;   // g11
  }
  // Phase B: per-wave single-qubit vectors q_i = G_layer0 * (RY RX |0>)
  if (lane < 12) {
    const float ang = atan2f(si[(size_t)s * 4096 + lane],
                             sr[(size_t)s * 4096 + lane]) * 0.5f;
    float sn, cs;
    sincosf(ang, &sn, &cs);
    const float e0r = cs * cs, e0i = sn * sn, e1r = sn * cs, e1i = -sn * cs;
    const float a = wts[(0 * 12 + lane) * 2 + 0] * 0.5f;
    const float b = wts[(0 * 12 + lane) * 2 + 1] * 0.5f;
    float sa, ca, sb, cb;
    sincosf(a, &sa, &ca);
    sincosf(b, &sb, &cb);
    const float g00r = cb * ca, g00i = sb * sa, g01r = -sb * ca, g01i = -cb * sa;
    const float g10r = sb * ca, g10i = -cb * sa, g11r = cb * ca, g11i = -sb * sa;
    const float q0r = g00r * e0r - g00i * e0i + g01r * e1r - g01i * e1i;
    const float q0i = g00r * e0i + g00i * e0r + g01r * e1i + g01i * e1r;
    const float q1r = g10r * e0r - g10i * e0i + g11r * e1r - g11i * e1i;
    const float q1i = g10r * e0i + g10i * e0r + g11r * e1i + g11i * e1r;
    qv[w][lane] = make_float4(q0r, q0i, q1r, q1i);
  }
  __syncthreads();
  // From here on, waves are fully independent (no more barriers).

  // Phase C: materialize product state into registers.
  float vr[64], vi[64];
  {
    float Lr, Li;
    {
      const float4 q0 = qv[w][0];
      const int b0 = (lane >> 5) & 1;
      Lr = b0 ? q0.z : q0.x;
      Li = b0 ? q0.w : q0.y;
      #pragma unroll
      for (int i = 1; i < 6; ++i) {
        const float4 qq = qv[w][i];
        const int bb = (lane >> (5 - i)) & 1;
        const float br = bb ? qq.z : qq.x, bi = bb ? qq.w : qq.y;
        const float nr = Lr * br - Li * bi, ni = Lr * bi + Li * br;
        Lr = nr; Li = ni;
      }
    }
    const float4 q6 = qv[w][6], q7 = qv[w][7], q8 = qv[w][8];
    const float4 q9 = qv[w][9], qA = qv[w][10], qB = qv[w][11];
    float hr[8], hi2[8], lr[8], li2[8];
    #pragma unroll
    for (int mM = 0; mM < 8; ++mM) {
      {
        const float ar = (mM & 4) ? q6.z : q6.x, ai = (mM & 4) ? q6.w : q6.y;
        const float br = (mM & 2) ? q7.z : q7.x, bi = (mM & 2) ? q7.w : q7.y;
        const float cr = (mM & 1) ? q8.z : q8.x, ci = (mM & 1) ? q8.w : q8.y;
        const float t1r = ar * br - ai * bi, t1i = ar * bi + ai * br;
        const float t3r = t1r * cr - t1i * ci, t3i = t1r * ci + t1i * cr;
        hr[mM]  = Lr * t3r - Li * t3i;   // fold lane-product L into the hi table
        hi2[mM] = Lr * t3i + Li * t3r;
      }
      {
        const float dr = (mM & 4) ? q9.z : q9.x, di = (mM & 4) ? q9.w : q9.y;
        const float er = (mM & 2) ? qA.z : qA.x, ei = (mM & 2) ? qA.w : qA.y;
        const float fr = (mM & 1) ? qB.z : qB.x, fi = (mM & 1) ? qB.w : qB.y;
        const float t4r = dr * er - di * ei, t4i = dr * ei + di * er;
        lr[mM]  = t4r * fr - t4i * fi;
        li2[mM] = t4r * fi + t4i * fr;
      }
    }
    #pragma unroll
    for (int j = 0; j < 64; ++j) {
      const int mh = j >> 3, ml = j & 7;
      vr[j] = hr[mh] * lr[ml] - hi2[mh] * li2[ml];
      vi[j] = hr[mh] * li2[ml] + hi2[mh] * lr[ml];
    }
  }

  // Phase D: 24 full-state gates (ref layers 1 and 2), CNOT rings deferred.
  apply_gate<0, 0>(vr, vi, lane, gt);
  apply_gate<0, 1>(vr, vi, lane, gt);
  apply_gate<0, 2>(vr, vi, lane, gt);
  apply_gate<0, 3>(vr, vi, lane, gt);
  apply_gate<0, 4>(vr, vi, lane, gt);
  apply_gate<0, 5>(vr, vi, lane, gt);
  apply_gate<0, 6>(vr, vi, lane, gt);
  apply_gate<0, 7>(vr, vi, lane, gt);
  apply_gate<0, 8>(vr, vi, lane, gt);
  apply_gate<0, 9>(vr, vi, lane, gt);
  apply_gate<0, 10>(vr, vi, lane, gt);
  apply_gate<0, 11>(vr, vi, lane, gt);
  apply_gate<1, 0>(vr, vi, lane, gt);
  apply_gate<1, 1>(vr, vi, lane, gt);
  apply_gate<1, 2>(vr, vi, lane, gt);
  apply_gate<1, 3>(vr, vi, lane, gt);
  apply_gate<1, 4>(vr, vi, lane, gt);
  apply_gate<1, 5>(vr, vi, lane, gt);
  apply_gate<1, 6>(vr, vi, lane, gt);
  apply_gate<1, 7>(vr, vi, lane, gt);
  apply_gate<1, 8>(vr, vi, lane, gt);
  apply_gate<1, 9>(vr, vi, lane, gt);
  apply_gate<1, 10>(vr, vi, lane, gt);
  apply_gate<1, 11>(vr, vi, lane, gt);

  // Phase E: y = sum_z |B_z|^2 * w(MP^3 z) + b, folded head weights.
  float hp[12];
  #pragma unroll
  for (int i = 0; i < 12; ++i) {
    const unsigned R = MP3.r[11 - i];
    const int neg = __builtin_popcount(lane & (int)(R >> 6)) & 1;
    const float h = hw[i];
    hp[i] = neg ? -h : h;
  }
  float acc = 0.f;
  #pragma unroll
  for (int j = 0; j < 64; ++j) {
    float wgt = 0.f;
    #pragma unroll
    for (int i = 0; i < 12; ++i) {
      wgt += (__builtin_popcount(j & (int)(MP3.r[11 - i] & 63u)) & 1) ? -hp[i]
                                                                      : hp[i];
    }
    acc += (vr[j] * vr[j] + vi[j] * vi[j]) * wgt;
  }
  #pragma unroll
  for (int off = 1; off < 64; off <<= 1) acc += __shfl_xor(acc, off, 64);
  if (lane == 0) out[s] = acc + hb[0];
}

extern "C" void kernel_launch(void* const* d_in, const int* in_sizes, int n_in,
                              void* d_out, int out_size, void* d_ws, size_t ws_size,
                              hipStream_t stream) {
  const float* sr  = (const float*)d_in[0];
  const float* si  = (const float*)d_in[1];
  const float* wts = (const float*)d_in[2];
  const float* hw  = (const float*)d_in[3];
  const float* hb  = (const float*)d_in[4];
  float* out = (float*)d_out;
  qsim_kernel<<<BATCH / 4, BLK, 0, stream>>>(sr, si, wts, hw, hb, out);
}